// Round 8
// baseline (2882.125 us; speedup 1.0000x reference)
//
#include <hip/hip_runtime.h>
#include <cstdint>
#include <cstddef>

#define NN 50000
#define EE 300000
#define HH 64
#define PP 3
#define GG 50
#define LL 2
#define CAP 32
#define SLOPE 0.01f

__device__ __forceinline__ float lrelu(float x){ return x >= 0.f ? x : SLOPE*x; }

// gstart[g] = first index i with batch[i] >= g (batch sorted); gstart[GG] = NN
__global__ void k_bounds(const int* __restrict__ batch, int* __restrict__ gstart){
    int g = threadIdx.x;
    if (g > GG) return;
    int lo = 0, hi = NN;
    while (lo < hi){ int mid = (lo + hi) >> 1; if (batch[mid] < g) lo = mid + 1; else hi = mid; }
    gstart[g] = lo;
}

// Single-pass bucket-CSR fill over all 6 edge sets.
__global__ void k_fill2(const int* __restrict__ uei, const float* __restrict__ uew,
                        const int* __restrict__ fei, const float* __restrict__ few,
                        int* __restrict__ cnt, int2* __restrict__ bucket){
    int t = blockIdx.x * blockDim.x + threadIdx.x;
    if (t >= 2 * PP * EE) return;
    int which = t / EE;
    int e = t - which * EE;
    const int* ei; const float* ew; int p;
    if (which < PP){ ei = uei; ew = uew; p = which; }
    else           { ei = fei; ew = few; p = which - PP; }
    int row = ei[(size_t)(p * 2 + 0) * EE + e];
    int col = ei[(size_t)(p * 2 + 1) * EE + e];
    float w = ew[(size_t)p * EE + e];
    int slot = atomicAdd(cnt + (size_t)which * NN + row, 1);
    if (slot < CAP)
        bucket[((size_t)which * NN + row) * CAP + slot] = make_int2(col, __float_as_int(w));
}

// Pre-permute ALL 12 fusion weight matrices: Wp12[t][q][o], t = conv*6 + layer*3 + p.
// q order: [self(64) | avg(64) | dir j-major], kref: [q | q | 128 + h*6 + j]
__global__ void k_wperm12(const float* __restrict__ S_fW, const float* __restrict__ F_fW,
                          float* __restrict__ Wp12){
    int gid = blockIdx.x * blockDim.x + threadIdx.x;   // 12*512*64
    int t = gid >> 15;
    int rem = gid & 32767;
    int q = rem >> 6, o = rem & 63;
    int conv = t / 6, layer = (t % 6) / 3, p = t % 3;
    const float* src = (conv ? F_fW : S_fW) + ((size_t)layer * PP + p) * 512 * HH;
    int kref;
    if (q < 128) kref = q;
    else { int r = q - 128; kref = 128 + (r & 63) * 6 + (r >> 6); }
    Wp12[gid] = src[(size_t)kref * HH + o];
}

// Register-blocked (N,64)@(64,64): 32 nodes/block, 4 waves, 8 nodes/wave.
__global__ __launch_bounds__(256) void k_lin64(const float* __restrict__ X,
                       const float* __restrict__ W, const float* __restrict__ b,
                       float* __restrict__ out){
    __shared__ float xs[32][HH];
    int nb = blockIdx.x * 32;
    int t = threadIdx.x;
    #pragma unroll
    for (int i = 0; i < 2; ++i){
        int idx = t + 256 * i;
        int r = idx >> 4, c4 = idx & 15;
        int n = nb + r;
        float4 v = make_float4(0.f, 0.f, 0.f, 0.f);
        if (n < NN) v = *reinterpret_cast<const float4*>(X + (size_t)n * HH + c4 * 4);
        *reinterpret_cast<float4*>(&xs[r][c4 * 4]) = v;
    }
    __syncthreads();
    int lane = t & 63, wave = t >> 6, nw = wave * 8;
    float acc[8];
    float bb = b[lane];
    #pragma unroll
    for (int i = 0; i < 8; ++i) acc[i] = bb;
    #pragma unroll 2
    for (int k = 0; k < HH; ++k){
        float wv = W[(size_t)k * HH + lane];
        #pragma unroll
        for (int i = 0; i < 8; ++i) acc[i] += xs[nw + i][k] * wv;
    }
    #pragma unroll
    for (int i = 0; i < 8; ++i){
        int n = nb + nw + i;
        if (n < NN) out[(size_t)n * HH + lane] = acc[i];
    }
}

// Whole OPDMP (3 hops) in one kernel. Block = 32 nodes, u[32][512] in LDS:
// row = [xt(64) | avg(64) | dir j-major(384)]. Per hop: aggregate -> LDS, K=512
// GEMM from LDS with pre-permuted Wp, accumulate lrelu(acc)*dw into accOut.
__global__ __launch_bounds__(256) void k_hop3(const float* __restrict__ xt,
        const int* __restrict__ cnt, const int2* __restrict__ bucket,
        const float* __restrict__ pe, const float* __restrict__ Wp3,
        const float* __restrict__ fb3, const float* __restrict__ dmat,
        const float* __restrict__ hb3, float* __restrict__ outb){
    __shared__ float u[32][512];
    int nb = blockIdx.x * 32;
    int t = threadIdx.x;
    int lane = t & 63, wave = t >> 6, nw = wave * 8;
    // stage xt rows into u[.][0:64]
    #pragma unroll
    for (int i = 0; i < 2; ++i){
        int idx = t + 256 * i;
        int r = idx >> 4, c4 = idx & 15;
        int n = nb + r;
        float4 v = make_float4(0.f, 0.f, 0.f, 0.f);
        if (n < NN) v = *reinterpret_cast<const float4*>(xt + (size_t)n * HH + c4 * 4);
        *reinterpret_cast<float4*>(&u[r][c4 * 4]) = v;
    }
    // softmax over hops (per output channel)
    float d0 = dmat[lane], d1 = dmat[64 + lane], d2 = dmat[128 + lane];
    float mx = fmaxf(d0, fmaxf(d1, d2));
    float e0 = expf(d0 - mx), e1 = expf(d1 - mx), e2 = expf(d2 - mx);
    float esum = e0 + e1 + e2;
    float dw0 = e0 / esum, dw1 = e1 / esum, dw2 = e2 / esum;
    float accOut[8];
    float hbs = hb3[lane] + hb3[64 + lane] + hb3[128 + lane];
    #pragma unroll
    for (int i = 0; i < 8; ++i) accOut[i] = hbs;

    for (int p = 0; p < 3; ++p){
        __syncthreads();
        // ---- phase A: aggregate 8 nodes per wave into LDS ----
        const int*  cntp = cnt + (size_t)p * NN;
        const int2* bp   = bucket + (size_t)p * NN * CAP;
        #pragma unroll
        for (int i = 0; i < 8; ++i){
            int n = nb + nw + i;
            float accA = 0.f, sumw = 0.f;
            float a0 = 0.f, a1 = 0.f, a2 = 0.f, a3 = 0.f, a4 = 0.f, a5 = 0.f;
            if (n < NN){
                int len = cntp[n]; if (len > CAP) len = CAP;
                const int2* b = bp + (size_t)n * CAP;
                float pr0 = pe[n * 3 + 0], pr1 = pe[n * 3 + 1], pr2 = pe[n * 3 + 2];
                for (int s = 0; s < len; ++s){
                    int2 m = b[s];
                    int col = m.x;
                    float w = __int_as_float(m.y);
                    float dd0 = pe[col * 3 + 0] - pr0;
                    float dd1 = pe[col * 3 + 1] - pr1;
                    float dd2 = pe[col * 3 + 2] - pr2;
                    float xv = xt[(size_t)col * HH + lane];
                    sumw += w;  accA += w * xv;
                    a0 += fmaxf(dd0, 0.f) * xv;  a3 += fmaxf(-dd0, 0.f) * xv;
                    a1 += fmaxf(dd1, 0.f) * xv;  a4 += fmaxf(-dd1, 0.f) * xv;
                    a2 += fmaxf(dd2, 0.f) * xv;  a5 += fmaxf(-dd2, 0.f) * xv;
                }
            }
            float di = (sumw == 0.f) ? 0.f : 1.f / sumw;
            int il = nw + i;
            u[il][64 + lane]           = accA * di;
            u[il][128 + 0 * 64 + lane] = a0 * di;
            u[il][128 + 1 * 64 + lane] = a1 * di;
            u[il][128 + 2 * 64 + lane] = a2 * di;
            u[il][128 + 3 * 64 + lane] = a3 * di;
            u[il][128 + 4 * 64 + lane] = a4 * di;
            u[il][128 + 5 * 64 + lane] = a5 * di;
        }
        __syncthreads();
        // ---- phase B: K=512 GEMM from LDS ----
        const float* wp = Wp3 + (size_t)p * 512 * HH + lane;
        float fbv = fb3[p * 64 + lane];
        float acc[8];
        #pragma unroll
        for (int i = 0; i < 8; ++i) acc[i] = fbv;
        #pragma unroll 2
        for (int k4 = 0; k4 < 128; ++k4){
            float w0 = wp[(k4 * 4 + 0) * 64];
            float w1 = wp[(k4 * 4 + 1) * 64];
            float w2 = wp[(k4 * 4 + 2) * 64];
            float w3 = wp[(k4 * 4 + 3) * 64];
            #pragma unroll
            for (int i = 0; i < 8; ++i){
                float4 uv = *reinterpret_cast<const float4*>(&u[nw + i][k4 * 4]);
                acc[i] += uv.x * w0 + uv.y * w1 + uv.z * w2 + uv.w * w3;
            }
        }
        float dw = (p == 0) ? dw0 : ((p == 1) ? dw1 : dw2);
        #pragma unroll
        for (int i = 0; i < 8; ++i) accOut[i] += lrelu(acc[i]) * dw;
    }
    #pragma unroll
    for (int i = 0; i < 8; ++i){
        int n = nb + nw + i;
        if (n < NN) outb[(size_t)n * HH + lane] = accOut[i];
    }
}

// per-graph column sums and sum-of-squares (direct write, one block per graph)
__global__ void k_stats(const float* __restrict__ X, const int* __restrict__ gstart,
                        float* __restrict__ sums, float* __restrict__ sumsq){
    int g = blockIdx.x;
    int tid = threadIdx.x;          // 1024 threads = 16 subs x 64 cols
    int o = tid & 63, sub = tid >> 6;
    int ns = gstart[g], ne = gstart[g + 1];
    float s = 0.f, q = 0.f;
    for (int n = ns + sub; n < ne; n += 16){
        float v = X[(size_t)n * 64 + o];
        s += v; q += v * v;
    }
    __shared__ float ls[16][64];
    __shared__ float lq[16][64];
    ls[sub][o] = s; lq[sub][o] = q;
    __syncthreads();
    if (sub == 0){
        #pragma unroll
        for (int k = 1; k < 16; ++k){ s += ls[k][o]; q += lq[k][o]; }
        sums[g * 64 + o] = s;
        sumsq[g * 64 + o] = q;
    }
}

// graph-norm + leaky_relu, in place.  var = E[x^2] - mean^2 * ms * (2 - ms)
__global__ void k_gnorm(float* __restrict__ X, const int* __restrict__ batch,
                        const int* __restrict__ gstart,
                        const float* __restrict__ sums, const float* __restrict__ sumsq,
                        const float* __restrict__ w, const float* __restrict__ b,
                        const float* __restrict__ ms){
    int gid = blockIdx.x * blockDim.x + threadIdx.x;
    if (gid >= NN * HH) return;
    int n = gid >> 6, o = gid & 63;
    int g = batch[n];
    float cnt = fmaxf((float)(gstart[g + 1] - gstart[g]), 1.f);
    float mean = sums[g * 64 + o] / cnt;
    float ex2 = sumsq[g * 64 + o] / cnt;
    float m = ms[o];
    float var = ex2 - mean * mean * m * (2.f - m);
    float v = (X[gid] - mean * m) * (1.f / sqrtf(var + 1e-5f)) * w[o] + b[o];
    X[gid] = lrelu(v);
}

// gate = sigmoid([h,fx] @ gate_W + gate_b); X = gate*h + (1-gate)*fx + X
__global__ __launch_bounds__(256) void k_gate2(const float* __restrict__ h,
                       const float* __restrict__ fx, const float* __restrict__ gW,
                       const float* __restrict__ gb, float* __restrict__ X){
    __shared__ float hs[32][HH];
    __shared__ float fs[32][HH];
    int nb = blockIdx.x * 32;
    int t = threadIdx.x;
    #pragma unroll
    for (int i = 0; i < 2; ++i){
        int idx = t + 256 * i;
        int r = idx >> 4, c4 = idx & 15;
        int n = nb + r;
        float4 vh = make_float4(0.f, 0.f, 0.f, 0.f);
        float4 vf = make_float4(0.f, 0.f, 0.f, 0.f);
        if (n < NN){
            vh = *reinterpret_cast<const float4*>(h  + (size_t)n * HH + c4 * 4);
            vf = *reinterpret_cast<const float4*>(fx + (size_t)n * HH + c4 * 4);
        }
        *reinterpret_cast<float4*>(&hs[r][c4 * 4]) = vh;
        *reinterpret_cast<float4*>(&fs[r][c4 * 4]) = vf;
    }
    __syncthreads();
    int lane = t & 63, wave = t >> 6, nw = wave * 8;
    float acc[8];
    float bb = gb[lane];
    #pragma unroll
    for (int i = 0; i < 8; ++i) acc[i] = bb;
    #pragma unroll 2
    for (int k = 0; k < HH; ++k){
        float w1 = gW[(size_t)k * HH + lane];
        float w2 = gW[(size_t)(64 + k) * HH + lane];
        #pragma unroll
        for (int i = 0; i < 8; ++i) acc[i] += hs[nw + i][k] * w1 + fs[nw + i][k] * w2;
    }
    #pragma unroll
    for (int i = 0; i < 8; ++i){
        int n = nb + nw + i;
        if (n < NN){
            float gt = 1.f / (1.f + expf(-acc[i]));
            float hv = hs[nw + i][lane];
            float fv = fs[nw + i][lane];
            size_t idx = (size_t)n * HH + lane;
            X[idx] = gt * hv + (1.f - gt) * fv + X[idx];
        }
    }
}

__global__ void k_finalout(const float* __restrict__ sums, const int* __restrict__ gstart,
                           float* __restrict__ out){
    int gid = blockIdx.x * blockDim.x + threadIdx.x;
    if (gid >= GG * HH) return;
    int g = gid >> 6;
    float cnt = fmaxf((float)(gstart[g + 1] - gstart[g]), 1.f);
    out[gid] = sums[gid] / cnt;
}

extern "C" void kernel_launch(void* const* d_in, const int* in_sizes, int n_in,
                              void* d_out, int out_size, void* d_ws, size_t ws_size,
                              hipStream_t stream) {
    const float* x_in   = (const float*)d_in[0];
    const float* pe     = (const float*)d_in[1];
    const int*   batch  = (const int*)d_in[2];
    const int*   uei    = (const int*)d_in[3];
    const float* uew    = (const float*)d_in[4];
    const int*   fei    = (const int*)d_in[5];
    const float* few    = (const float*)d_in[6];
    const float* emb_W  = (const float*)d_in[7];
    const float* emb_b  = (const float*)d_in[8];
    const float* S_lin_W= (const float*)d_in[9];
    const float* S_lin_b= (const float*)d_in[10];
    const float* S_d    = (const float*)d_in[11];
    const float* S_hb   = (const float*)d_in[12];
    const float* S_fW   = (const float*)d_in[13];
    const float* S_fb   = (const float*)d_in[14];
    const float* F_lin_W= (const float*)d_in[15];
    const float* F_lin_b= (const float*)d_in[16];
    const float* F_d    = (const float*)d_in[17];
    const float* F_hb   = (const float*)d_in[18];
    const float* F_fW   = (const float*)d_in[19];
    const float* F_fb   = (const float*)d_in[20];
    const float* nS_w   = (const float*)d_in[21];
    const float* nS_b   = (const float*)d_in[22];
    const float* nS_m   = (const float*)d_in[23];
    const float* nF_w   = (const float*)d_in[24];
    const float* nF_b   = (const float*)d_in[25];
    const float* nF_m   = (const float*)d_in[26];
    const float* gate_W = (const float*)d_in[27];
    const float* gate_b = (const float*)d_in[28];
    float* out = (float*)d_out;

    size_t off = 0;
    auto alloc = [&](size_t bytes)->void*{
        void* p = (char*)d_ws + off;
        off += (bytes + 255) & ~(size_t)255;
        return p;
    };
    float* xbuf   = (float*)alloc((size_t)NN * HH * 4);
    float* hbuf   = (float*)alloc((size_t)NN * HH * 4);
    float* fxbuf  = (float*)alloc((size_t)NN * HH * 4);
    float* xt     = (float*)alloc((size_t)NN * HH * 4);
    float* Wp12   = (float*)alloc((size_t)12 * 512 * HH * 4);
    int*   cnt    = (int*)  alloc((size_t)6 * NN * 4);
    int2*  bucket = (int2*) alloc((size_t)6 * NN * CAP * 8);
    int*   gstart = (int*)  alloc((GG + 1) * 4);
    float* sums   = (float*)alloc(GG * HH * 4);
    float* sumsq  = (float*)alloc(GG * HH * 4);

    const int BLK = 256;
    const int gridNH = (NN * HH) / BLK;          // 12500
    const int gridN32 = (NN + 31) / 32;          // 1563
    const int gridEdges = (2 * PP * EE + BLK - 1) / BLK;

    k_bounds<<<1, 64, 0, stream>>>(batch, gstart);
    hipMemsetAsync(cnt, 0, (size_t)6 * NN * 4, stream);
    k_fill2<<<gridEdges, BLK, 0, stream>>>(uei, uew, fei, few, cnt, bucket);
    k_wperm12<<<(12 * 512 * HH) / BLK, BLK, 0, stream>>>(S_fW, F_fW, Wp12);
    k_lin64<<<gridN32, BLK, 0, stream>>>(x_in, emb_W, emb_b, xbuf);

    auto gnorm = [&](float* X, const float* w, const float* b, const float* ms){
        k_stats<<<GG, 1024, 0, stream>>>(X, gstart, sums, sumsq);
        k_gnorm<<<gridNH, BLK, 0, stream>>>(X, batch, gstart, sums, sumsq, w, b, ms);
    };

    for (int i = 0; i < LL; ++i){
        // S conv (u edges, which 0..2)
        k_lin64<<<gridN32, BLK, 0, stream>>>(xbuf, S_lin_W + (size_t)i * HH * HH,
                                             S_lin_b + (size_t)i * HH, xt);
        k_hop3<<<gridN32, BLK, 0, stream>>>(xt, cnt, bucket, pe,
                Wp12 + (size_t)(0 * 6 + i * 3) * 512 * HH,
                S_fb + (size_t)i * PP * HH, S_d + (size_t)i * PP * HH,
                S_hb + (size_t)i * PP * HH, hbuf);
        gnorm(hbuf, nS_w + (size_t)i * HH, nS_b + (size_t)i * HH, nS_m + (size_t)i * HH);
        // F conv (f edges, which 3..5)
        k_lin64<<<gridN32, BLK, 0, stream>>>(hbuf, F_lin_W + (size_t)i * HH * HH,
                                             F_lin_b + (size_t)i * HH, xt);
        k_hop3<<<gridN32, BLK, 0, stream>>>(xt, cnt + (size_t)PP * NN,
                bucket + (size_t)PP * NN * CAP, pe,
                Wp12 + (size_t)(1 * 6 + i * 3) * 512 * HH,
                F_fb + (size_t)i * PP * HH, F_d + (size_t)i * PP * HH,
                F_hb + (size_t)i * PP * HH, fxbuf);
        gnorm(fxbuf, nF_w + (size_t)i * HH, nF_b + (size_t)i * HH, nF_m + (size_t)i * HH);
        k_gate2<<<gridN32, BLK, 0, stream>>>(hbuf, fxbuf, gate_W, gate_b, xbuf);
    }

    k_stats<<<GG, 1024, 0, stream>>>(xbuf, gstart, sums, sumsq);
    k_finalout<<<(GG * HH + BLK - 1) / BLK, BLK, 0, stream>>>(sums, gstart, out);
}

// Round 9
// 2079.726 us; speedup vs baseline: 1.3858x; 1.3858x over previous
//
#include <hip/hip_runtime.h>
#include <cstdint>
#include <cstddef>

#define NN 50000
#define EE 300000
#define HH 64
#define PP 3
#define GG 50
#define LL 2
#define CAP 32
#define SLOPE 0.01f

__device__ __forceinline__ float lrelu(float x){ return x >= 0.f ? x : SLOPE*x; }

// gstart[g] = first index i with batch[i] >= g (batch sorted); gstart[GG] = NN
__global__ void k_bounds(const int* __restrict__ batch, int* __restrict__ gstart){
    int g = threadIdx.x;
    if (g > GG) return;
    int lo = 0, hi = NN;
    while (lo < hi){ int mid = (lo + hi) >> 1; if (batch[mid] < g) lo = mid + 1; else hi = mid; }
    gstart[g] = lo;
}

// Single-pass bucket-CSR fill over all 6 edge sets.
__global__ void k_fill2(const int* __restrict__ uei, const float* __restrict__ uew,
                        const int* __restrict__ fei, const float* __restrict__ few,
                        int* __restrict__ cnt, int2* __restrict__ bucket){
    int t = blockIdx.x * blockDim.x + threadIdx.x;
    if (t >= 2 * PP * EE) return;
    int which = t / EE;
    int e = t - which * EE;
    const int* ei; const float* ew; int p;
    if (which < PP){ ei = uei; ew = uew; p = which; }
    else           { ei = fei; ew = few; p = which - PP; }
    int row = ei[(size_t)(p * 2 + 0) * EE + e];
    int col = ei[(size_t)(p * 2 + 1) * EE + e];
    float w = ew[(size_t)p * EE + e];
    int slot = atomicAdd(cnt + (size_t)which * NN + row, 1);
    if (slot < CAP)
        bucket[((size_t)which * NN + row) * CAP + slot] = make_int2(col, __float_as_int(w));
}

// Pre-permute ALL 12 fusion weight matrices: Wp12[t][q][o], t = conv*6 + layer*3 + p.
// q order: [self(64) | avg(64) | dir j-major], kref: [q | q | 128 + h*6 + j]
__global__ void k_wperm12(const float* __restrict__ S_fW, const float* __restrict__ F_fW,
                          float* __restrict__ Wp12){
    int gid = blockIdx.x * blockDim.x + threadIdx.x;   // 12*512*64
    int t = gid >> 15;
    int rem = gid & 32767;
    int q = rem >> 6, o = rem & 63;
    int conv = t / 6, layer = (t % 6) / 3, p = t % 3;
    const float* src = (conv ? F_fW : S_fW) + ((size_t)layer * PP + p) * 512 * HH;
    int kref;
    if (q < 128) kref = q;
    else { int r = q - 128; kref = 128 + (r & 63) * 6 + (r >> 6); }
    Wp12[gid] = src[(size_t)kref * HH + o];
}

// Register-blocked (N,64)@(64,64): 32 nodes/block, 4 waves, 8 nodes/wave.
__global__ __launch_bounds__(256) void k_lin64(const float* __restrict__ X,
                       const float* __restrict__ W, const float* __restrict__ b,
                       float* __restrict__ out){
    __shared__ float xs[32][HH];
    int nb = blockIdx.x * 32;
    int t = threadIdx.x;
    #pragma unroll
    for (int i = 0; i < 2; ++i){
        int idx = t + 256 * i;
        int r = idx >> 4, c4 = idx & 15;
        int n = nb + r;
        float4 v = make_float4(0.f, 0.f, 0.f, 0.f);
        if (n < NN) v = *reinterpret_cast<const float4*>(X + (size_t)n * HH + c4 * 4);
        *reinterpret_cast<float4*>(&xs[r][c4 * 4]) = v;
    }
    __syncthreads();
    int lane = t & 63, wave = t >> 6, nw = wave * 8;
    float acc[8];
    float bb = b[lane];
    #pragma unroll
    for (int i = 0; i < 8; ++i) acc[i] = bb;
    #pragma unroll 2
    for (int k = 0; k < HH; ++k){
        float wv = W[(size_t)k * HH + lane];
        #pragma unroll
        for (int i = 0; i < 8; ++i) acc[i] += xs[nw + i][k] * wv;
    }
    #pragma unroll
    for (int i = 0; i < 8; ++i){
        int n = nb + nw + i;
        if (n < NN) out[(size_t)n * HH + lane] = acc[i];
    }
}

// Whole OPDMP (3 hops) in one kernel. Block = 16 nodes (32 KB LDS -> 5 blocks/CU),
// u[16][512]: row = [xt(64) | avg(64) | dir j-major(384)]. Per hop: aggregate ->
// LDS (4 nodes/wave), K=512 GEMM from LDS with pre-permuted Wp, accumulate
// lrelu(acc)*dw into accOut; out written once.  Grid = NN/16 = 3125 exact.
__global__ __launch_bounds__(256) void k_hop3(const float* __restrict__ xt,
        const int* __restrict__ cnt, const int2* __restrict__ bucket,
        const float* __restrict__ pe, const float* __restrict__ Wp3,
        const float* __restrict__ fb3, const float* __restrict__ dmat,
        const float* __restrict__ hb3, float* __restrict__ outb){
    __shared__ float u[16][512];
    int nb = blockIdx.x * 16;
    int t = threadIdx.x;
    int lane = t & 63, wave = t >> 6, nw = wave * 4;
    // stage xt rows into u[.][0:64]  (16 rows x 16 float4 = 256 threads exactly)
    {
        int r = t >> 4, c4 = t & 15;
        float4 v = *reinterpret_cast<const float4*>(xt + (size_t)(nb + r) * HH + c4 * 4);
        *reinterpret_cast<float4*>(&u[r][c4 * 4]) = v;
    }
    // softmax over hops (per output channel)
    float d0 = dmat[lane], d1 = dmat[64 + lane], d2 = dmat[128 + lane];
    float mx = fmaxf(d0, fmaxf(d1, d2));
    float e0 = expf(d0 - mx), e1 = expf(d1 - mx), e2 = expf(d2 - mx);
    float esum = e0 + e1 + e2;
    float dw0 = e0 / esum, dw1 = e1 / esum, dw2 = e2 / esum;
    float accOut[4];
    float hbs = hb3[lane] + hb3[64 + lane] + hb3[128 + lane];
    #pragma unroll
    for (int i = 0; i < 4; ++i) accOut[i] = hbs;

    for (int p = 0; p < 3; ++p){
        __syncthreads();
        // ---- phase A: aggregate 4 nodes per wave into LDS ----
        const int*  cntp = cnt + (size_t)p * NN;
        const int2* bp   = bucket + (size_t)p * NN * CAP;
        #pragma unroll
        for (int i = 0; i < 4; ++i){
            int n = nb + nw + i;
            float accA = 0.f, sumw = 0.f;
            float a0 = 0.f, a1 = 0.f, a2 = 0.f, a3 = 0.f, a4 = 0.f, a5 = 0.f;
            int len = cntp[n]; if (len > CAP) len = CAP;
            const int2* b = bp + (size_t)n * CAP;
            float pr0 = pe[n * 3 + 0], pr1 = pe[n * 3 + 1], pr2 = pe[n * 3 + 2];
            for (int s = 0; s < len; ++s){
                int2 m = b[s];
                int col = m.x;
                float w = __int_as_float(m.y);
                float dd0 = pe[col * 3 + 0] - pr0;
                float dd1 = pe[col * 3 + 1] - pr1;
                float dd2 = pe[col * 3 + 2] - pr2;
                float xv = xt[(size_t)col * HH + lane];
                sumw += w;  accA += w * xv;
                a0 += fmaxf(dd0, 0.f) * xv;  a3 += fmaxf(-dd0, 0.f) * xv;
                a1 += fmaxf(dd1, 0.f) * xv;  a4 += fmaxf(-dd1, 0.f) * xv;
                a2 += fmaxf(dd2, 0.f) * xv;  a5 += fmaxf(-dd2, 0.f) * xv;
            }
            float di = (sumw == 0.f) ? 0.f : 1.f / sumw;
            int il = nw + i;
            u[il][64 + lane]           = accA * di;
            u[il][128 + 0 * 64 + lane] = a0 * di;
            u[il][128 + 1 * 64 + lane] = a1 * di;
            u[il][128 + 2 * 64 + lane] = a2 * di;
            u[il][128 + 3 * 64 + lane] = a3 * di;
            u[il][128 + 4 * 64 + lane] = a4 * di;
            u[il][128 + 5 * 64 + lane] = a5 * di;
        }
        __syncthreads();
        // ---- phase B: K=512 GEMM from LDS ----
        const float* wp = Wp3 + (size_t)p * 512 * HH + lane;
        float fbv = fb3[p * 64 + lane];
        float acc[4];
        #pragma unroll
        for (int i = 0; i < 4; ++i) acc[i] = fbv;
        #pragma unroll 2
        for (int k4 = 0; k4 < 128; ++k4){
            float w0 = wp[(k4 * 4 + 0) * 64];
            float w1 = wp[(k4 * 4 + 1) * 64];
            float w2 = wp[(k4 * 4 + 2) * 64];
            float w3 = wp[(k4 * 4 + 3) * 64];
            #pragma unroll
            for (int i = 0; i < 4; ++i){
                float4 uv = *reinterpret_cast<const float4*>(&u[nw + i][k4 * 4]);
                acc[i] += uv.x * w0 + uv.y * w1 + uv.z * w2 + uv.w * w3;
            }
        }
        float dw = (p == 0) ? dw0 : ((p == 1) ? dw1 : dw2);
        #pragma unroll
        for (int i = 0; i < 4; ++i) accOut[i] += lrelu(acc[i]) * dw;
    }
    #pragma unroll
    for (int i = 0; i < 4; ++i)
        outb[(size_t)(nb + nw + i) * HH + lane] = accOut[i];
}

// per-graph column sums and sum-of-squares (direct write, one block per graph)
__global__ void k_stats(const float* __restrict__ X, const int* __restrict__ gstart,
                        float* __restrict__ sums, float* __restrict__ sumsq){
    int g = blockIdx.x;
    int tid = threadIdx.x;          // 1024 threads = 16 subs x 64 cols
    int o = tid & 63, sub = tid >> 6;
    int ns = gstart[g], ne = gstart[g + 1];
    float s = 0.f, q = 0.f;
    for (int n = ns + sub; n < ne; n += 16){
        float v = X[(size_t)n * 64 + o];
        s += v; q += v * v;
    }
    __shared__ float ls[16][64];
    __shared__ float lq[16][64];
    ls[sub][o] = s; lq[sub][o] = q;
    __syncthreads();
    if (sub == 0){
        #pragma unroll
        for (int k = 1; k < 16; ++k){ s += ls[k][o]; q += lq[k][o]; }
        sums[g * 64 + o] = s;
        sumsq[g * 64 + o] = q;
    }
}

// graph-norm + leaky_relu, in place.  var = E[x^2] - mean^2 * ms * (2 - ms)
__global__ void k_gnorm(float* __restrict__ X, const int* __restrict__ batch,
                        const int* __restrict__ gstart,
                        const float* __restrict__ sums, const float* __restrict__ sumsq,
                        const float* __restrict__ w, const float* __restrict__ b,
                        const float* __restrict__ ms){
    int gid = blockIdx.x * blockDim.x + threadIdx.x;
    if (gid >= NN * HH) return;
    int n = gid >> 6, o = gid & 63;
    int g = batch[n];
    float cnt = fmaxf((float)(gstart[g + 1] - gstart[g]), 1.f);
    float mean = sums[g * 64 + o] / cnt;
    float ex2 = sumsq[g * 64 + o] / cnt;
    float m = ms[o];
    float var = ex2 - mean * mean * m * (2.f - m);
    float v = (X[gid] - mean * m) * (1.f / sqrtf(var + 1e-5f)) * w[o] + b[o];
    X[gid] = lrelu(v);
}

// gate = sigmoid([h,fx] @ gate_W + gate_b); X = gate*h + (1-gate)*fx + X
__global__ __launch_bounds__(256) void k_gate2(const float* __restrict__ h,
                       const float* __restrict__ fx, const float* __restrict__ gW,
                       const float* __restrict__ gb, float* __restrict__ X){
    __shared__ float hs[32][HH];
    __shared__ float fs[32][HH];
    int nb = blockIdx.x * 32;
    int t = threadIdx.x;
    #pragma unroll
    for (int i = 0; i < 2; ++i){
        int idx = t + 256 * i;
        int r = idx >> 4, c4 = idx & 15;
        int n = nb + r;
        float4 vh = make_float4(0.f, 0.f, 0.f, 0.f);
        float4 vf = make_float4(0.f, 0.f, 0.f, 0.f);
        if (n < NN){
            vh = *reinterpret_cast<const float4*>(h  + (size_t)n * HH + c4 * 4);
            vf = *reinterpret_cast<const float4*>(fx + (size_t)n * HH + c4 * 4);
        }
        *reinterpret_cast<float4*>(&hs[r][c4 * 4]) = vh;
        *reinterpret_cast<float4*>(&fs[r][c4 * 4]) = vf;
    }
    __syncthreads();
    int lane = t & 63, wave = t >> 6, nw = wave * 8;
    float acc[8];
    float bb = gb[lane];
    #pragma unroll
    for (int i = 0; i < 8; ++i) acc[i] = bb;
    #pragma unroll 2
    for (int k = 0; k < HH; ++k){
        float w1 = gW[(size_t)k * HH + lane];
        float w2 = gW[(size_t)(64 + k) * HH + lane];
        #pragma unroll
        for (int i = 0; i < 8; ++i) acc[i] += hs[nw + i][k] * w1 + fs[nw + i][k] * w2;
    }
    #pragma unroll
    for (int i = 0; i < 8; ++i){
        int n = nb + nw + i;
        if (n < NN){
            float gt = 1.f / (1.f + expf(-acc[i]));
            float hv = hs[nw + i][lane];
            float fv = fs[nw + i][lane];
            size_t idx = (size_t)n * HH + lane;
            X[idx] = gt * hv + (1.f - gt) * fv + X[idx];
        }
    }
}

__global__ void k_finalout(const float* __restrict__ sums, const int* __restrict__ gstart,
                           float* __restrict__ out){
    int gid = blockIdx.x * blockDim.x + threadIdx.x;
    if (gid >= GG * HH) return;
    int g = gid >> 6;
    float cnt = fmaxf((float)(gstart[g + 1] - gstart[g]), 1.f);
    out[gid] = sums[gid] / cnt;
}

extern "C" void kernel_launch(void* const* d_in, const int* in_sizes, int n_in,
                              void* d_out, int out_size, void* d_ws, size_t ws_size,
                              hipStream_t stream) {
    const float* x_in   = (const float*)d_in[0];
    const float* pe     = (const float*)d_in[1];
    const int*   batch  = (const int*)d_in[2];
    const int*   uei    = (const int*)d_in[3];
    const float* uew    = (const float*)d_in[4];
    const int*   fei    = (const int*)d_in[5];
    const float* few    = (const float*)d_in[6];
    const float* emb_W  = (const float*)d_in[7];
    const float* emb_b  = (const float*)d_in[8];
    const float* S_lin_W= (const float*)d_in[9];
    const float* S_lin_b= (const float*)d_in[10];
    const float* S_d    = (const float*)d_in[11];
    const float* S_hb   = (const float*)d_in[12];
    const float* S_fW   = (const float*)d_in[13];
    const float* S_fb   = (const float*)d_in[14];
    const float* F_lin_W= (const float*)d_in[15];
    const float* F_lin_b= (const float*)d_in[16];
    const float* F_d    = (const float*)d_in[17];
    const float* F_hb   = (const float*)d_in[18];
    const float* F_fW   = (const float*)d_in[19];
    const float* F_fb   = (const float*)d_in[20];
    const float* nS_w   = (const float*)d_in[21];
    const float* nS_b   = (const float*)d_in[22];
    const float* nS_m   = (const float*)d_in[23];
    const float* nF_w   = (const float*)d_in[24];
    const float* nF_b   = (const float*)d_in[25];
    const float* nF_m   = (const float*)d_in[26];
    const float* gate_W = (const float*)d_in[27];
    const float* gate_b = (const float*)d_in[28];
    float* out = (float*)d_out;

    size_t off = 0;
    auto alloc = [&](size_t bytes)->void*{
        void* p = (char*)d_ws + off;
        off += (bytes + 255) & ~(size_t)255;
        return p;
    };
    float* xbuf   = (float*)alloc((size_t)NN * HH * 4);
    float* hbuf   = (float*)alloc((size_t)NN * HH * 4);
    float* fxbuf  = (float*)alloc((size_t)NN * HH * 4);
    float* xt     = (float*)alloc((size_t)NN * HH * 4);
    float* Wp12   = (float*)alloc((size_t)12 * 512 * HH * 4);
    int*   cnt    = (int*)  alloc((size_t)6 * NN * 4);
    int2*  bucket = (int2*) alloc((size_t)6 * NN * CAP * 8);
    int*   gstart = (int*)  alloc((GG + 1) * 4);
    float* sums   = (float*)alloc(GG * HH * 4);
    float* sumsq  = (float*)alloc(GG * HH * 4);

    const int BLK = 256;
    const int gridNH = (NN * HH) / BLK;          // 12500
    const int gridN32 = (NN + 31) / 32;          // 1563
    const int gridHop = NN / 16;                 // 3125 exact
    const int gridEdges = (2 * PP * EE + BLK - 1) / BLK;

    k_bounds<<<1, 64, 0, stream>>>(batch, gstart);
    hipMemsetAsync(cnt, 0, (size_t)6 * NN * 4, stream);
    k_fill2<<<gridEdges, BLK, 0, stream>>>(uei, uew, fei, few, cnt, bucket);
    k_wperm12<<<(12 * 512 * HH) / BLK, BLK, 0, stream>>>(S_fW, F_fW, Wp12);
    k_lin64<<<gridN32, BLK, 0, stream>>>(x_in, emb_W, emb_b, xbuf);

    auto gnorm = [&](float* X, const float* w, const float* b, const float* ms){
        k_stats<<<GG, 1024, 0, stream>>>(X, gstart, sums, sumsq);
        k_gnorm<<<gridNH, BLK, 0, stream>>>(X, batch, gstart, sums, sumsq, w, b, ms);
    };

    for (int i = 0; i < LL; ++i){
        // S conv (u edges, which 0..2)
        k_lin64<<<gridN32, BLK, 0, stream>>>(xbuf, S_lin_W + (size_t)i * HH * HH,
                                             S_lin_b + (size_t)i * HH, xt);
        k_hop3<<<gridHop, BLK, 0, stream>>>(xt, cnt, bucket, pe,
                Wp12 + (size_t)(0 * 6 + i * 3) * 512 * HH,
                S_fb + (size_t)i * PP * HH, S_d + (size_t)i * PP * HH,
                S_hb + (size_t)i * PP * HH, hbuf);
        gnorm(hbuf, nS_w + (size_t)i * HH, nS_b + (size_t)i * HH, nS_m + (size_t)i * HH);
        // F conv (f edges, which 3..5)
        k_lin64<<<gridN32, BLK, 0, stream>>>(hbuf, F_lin_W + (size_t)i * HH * HH,
                                             F_lin_b + (size_t)i * HH, xt);
        k_hop3<<<gridHop, BLK, 0, stream>>>(xt, cnt + (size_t)PP * NN,
                bucket + (size_t)PP * NN * CAP, pe,
                Wp12 + (size_t)(1 * 6 + i * 3) * 512 * HH,
                F_fb + (size_t)i * PP * HH, F_d + (size_t)i * PP * HH,
                F_hb + (size_t)i * PP * HH, fxbuf);
        gnorm(fxbuf, nF_w + (size_t)i * HH, nF_b + (size_t)i * HH, nF_m + (size_t)i * HH);
        k_gate2<<<gridN32, BLK, 0, stream>>>(hbuf, fxbuf, gate_W, gate_b, xbuf);
    }

    k_stats<<<GG, 1024, 0, stream>>>(xbuf, gstart, sums, sumsq);
    k_finalout<<<(GG * HH + BLK - 1) / BLK, BLK, 0, stream>>>(sums, gstart, out);
}